// Round 2
// 119.945 us; speedup vs baseline: 1.0002x; 1.0002x over previous
//
#include <hip/hip_runtime.h>
#include <math.h>

#define QN 128
#define SN 512
#define DN 768
#define TDN 1536
#define CN 64
#define KSPLIT 4
#define KCH 192   // 768 / KSPLIT

#define A_ROWS 640                  // 128 query + 512 support rows
#define A_FLOATS (A_ROWS * DN)      // 491520
#define B_FLOATS (TDN * TDN)        // 2359296
#define Q_FLOATS (QN * DN)          // 98304

#define HQP_ELEMS (KSPLIT * QN * TDN)
#define HSP_ELEMS (KSPLIT * SN * TDN)
#define ZERO_ELEMS (QN * CN)

typedef short short8 __attribute__((ext_vector_type(8)));
typedef float f32x4 __attribute__((ext_vector_type(4)));

__device__ __forceinline__ short bf16_rtn(float x) {
    unsigned u = __float_as_uint(x);
    return (short)((u + 0x7fffu + ((u >> 16) & 1u)) >> 16);
}
__device__ __forceinline__ float bf16_tof(short s) {
    return __uint_as_float(((unsigned)(unsigned short)s) << 16);
}

// global -> LDS direct 16B copy (m97 pattern). LDS base must be wave-uniform;
// HW writes lane l's 16 bytes at base + l*16. Direct addrspacecast form.
__device__ __forceinline__ void gload_lds16(const short* g, short* l) {
    __builtin_amdgcn_global_load_lds(
        (const __attribute__((address_space(1))) void*)g,
        (__attribute__((address_space(3))) void*)l,
        16, 0, 0);
}

// ---------------------------------------------------------------------------
// One-time f32 -> bf16 hi/lo split of A (query|support rows) and W1.
// Removes the 4-12x redundant per-tile conversion the old gemm staging did.
// Also zeroes aggbuf (blocks 0..7) and out[0]. grid 1392 x 256: each thread
// converts exactly 8 floats (1392*256*8 = 2,850,816 = A_FLOATS + B_FLOATS).
// ---------------------------------------------------------------------------
__global__ __launch_bounds__(256) void convert_kernel(
    const float* __restrict__ query, const float* __restrict__ support,
    const float* __restrict__ W1,
    short* __restrict__ Ah, short* __restrict__ Al,
    short* __restrict__ Bh, short* __restrict__ Bl,
    float* __restrict__ zbuf, float* __restrict__ out)
{
    const int flat = blockIdx.x * 256 + threadIdx.x;
    if (blockIdx.x < 8) {            // 8*256*4 = 8192 = QN*CN
        *(float4*)&zbuf[flat * 4] = make_float4(0.f, 0.f, 0.f, 0.f);
        if (flat == 0) out[0] = 0.0f;
    }
    const long long i8 = (long long)flat * 8;
    const float* src;
    short *dh, *dl;
    if (i8 < A_FLOATS) {             // A space: rows 0..127 query, 128..639 support
        src = (i8 < Q_FLOATS) ? (query + i8) : (support + (i8 - Q_FLOATS));
        dh = Ah + i8; dl = Al + i8;
    } else {                         // B space: W1 row-major [1536][1536]
        long long o = i8 - A_FLOATS;
        src = W1 + o; dh = Bh + o; dl = Bl + o;
    }
    float4 v0 = *(const float4*)src;
    float4 v1 = *(const float4*)(src + 4);
    float f[8] = {v0.x, v0.y, v0.z, v0.w, v1.x, v1.y, v1.z, v1.w};
    short8 hi, lo;
    #pragma unroll
    for (int i = 0; i < 8; ++i) {
        short h = bf16_rtn(f[i]);
        hi[i] = h;
        lo[i] = bf16_rtn(f[i] - bf16_tof(h));
    }
    *(short8*)dh = hi;
    *(short8*)dl = lo;
}

// ---------------------------------------------------------------------------
// bf16x3 MFMA GEMM: out[m][n] = sum_k A[m][k]*W1[n][Koff+k], split-K 4.
// grid (12, 5, 4) = 240 blocks; block 256 = 4 waves, each wave a 64x64
// quadrant of the 128x128 tile as 4x4 subtiles of 16x16x32 MFMA.
// Staging is pure global_load_lds dwordx4 from the preconverted bf16 planes:
// wave w stages plane w in {Ah, Al, Bh, Bl}, 8 calls x 1KB per step.
// LDS planes are UNPADDED [128][32] bf16 (8KB): lane l of a staging call
// covers LDS offset l*16 B == row(l>>2)*64 + (l&3)*16 -> linear, as HW needs.
// 3 MFMAs (hh, hl, lh) per pair give ~2^-18 relative error.
// ---------------------------------------------------------------------------
__global__ __launch_bounds__(256) void gemm_kernel(
    const short* __restrict__ Ah, const short* __restrict__ Al,
    const short* __restrict__ Bh, const short* __restrict__ Bl,
    float* __restrict__ hqp, float* __restrict__ hsp)
{
    const int nt = blockIdx.x;   // 0..11  N tile
    const int mt = blockIdx.y;   // 0..4   M tile (0 = query, 1..4 = support)
    const int kz = blockIdx.z;   // 0..3   K split
    const int tid  = threadIdx.x;
    const int lane = tid & 63;
    const int w    = tid >> 6;

    __shared__ short lds[2][4][128 * 32];   // [buf][Ah,Al,Bh,Bl] = 64 KB

    const int Koff = (mt == 0) ? 0 : DN;
    float* Cout = (mt == 0)
        ? (hqp + (size_t)kz * QN * TDN)
        : (hsp + (size_t)kz * SN * TDN + (size_t)(mt - 1) * 128 * TDN);

    // staging source: wave w stages plane w; per-lane global addr, uniform LDS base
    const short* G;
    int rs, grow0, gcol0;
    if (w < 2) { G = (w == 0) ? Ah : Al; rs = DN;  grow0 = mt * 128; gcol0 = kz * KCH; }
    else       { G = (w == 2) ? Bh : Bl; rs = TDN; grow0 = nt * 128; gcol0 = Koff + kz * KCH; }
    const short* gsrc = G + (size_t)(grow0 + (lane >> 2)) * rs + gcol0 + (lane & 3) * 8;
    const size_t cstride = (size_t)16 * rs;   // 16 rows per 1KB call

    f32x4 acc[4][4];
    #pragma unroll
    for (int i = 0; i < 4; ++i)
        #pragma unroll
        for (int j = 0; j < 4; ++j)
            acc[i][j] = (f32x4){0.f, 0.f, 0.f, 0.f};

    {   // prologue: stage step 0 into buf 0
        short* lb = &lds[0][w][0];
        #pragma unroll
        for (int c = 0; c < 8; ++c)
            gload_lds16(gsrc + c * cstride, lb + c * 512);
    }
    __syncthreads();   // compiler drains vmcnt(0) before s_barrier

    const int lm    = lane & 15;
    const int quad  = lane >> 4;
    const int wrow0 = (w >> 1) * 64;
    const int wcol0 = (w & 1) * 64;

    int buf = 0;
    for (int step = 0; step < 6; ++step) {
        if (step < 5) {   // issue next-step loads first; they drain at the barrier
            short* lb = &lds[buf ^ 1][w][0];
            const short* gs = gsrc + (step + 1) * 32;
            #pragma unroll
            for (int c = 0; c < 8; ++c)
                gload_lds16(gs + c * cstride, lb + c * 512);
        }

        const short* Ahs = &lds[buf][0][0];
        const short* Als = &lds[buf][1][0];
        const short* Bhs = &lds[buf][2][0];
        const short* Bls = &lds[buf][3][0];

        short8 ah[4], al[4], bh[4], bl[4];
        #pragma unroll
        for (int mi = 0; mi < 4; ++mi) {
            int off = (wrow0 + mi * 16 + lm) * 32 + quad * 8;
            ah[mi] = *(const short8*)&Ahs[off];
            al[mi] = *(const short8*)&Als[off];
        }
        #pragma unroll
        for (int ni = 0; ni < 4; ++ni) {
            int off = (wcol0 + ni * 16 + lm) * 32 + quad * 8;
            bh[ni] = *(const short8*)&Bhs[off];
            bl[ni] = *(const short8*)&Bls[off];
        }
        #pragma unroll
        for (int mi = 0; mi < 4; ++mi)
            #pragma unroll
            for (int ni = 0; ni < 4; ++ni) {
                acc[mi][ni] = __builtin_amdgcn_mfma_f32_16x16x32_bf16(ah[mi], bh[ni], acc[mi][ni], 0, 0, 0);
                acc[mi][ni] = __builtin_amdgcn_mfma_f32_16x16x32_bf16(ah[mi], bl[ni], acc[mi][ni], 0, 0, 0);
                acc[mi][ni] = __builtin_amdgcn_mfma_f32_16x16x32_bf16(al[mi], bh[ni], acc[mi][ni], 0, 0, 0);
            }

        __syncthreads();
        buf ^= 1;
    }

    // epilogue: C/D layout col=lane&15, row=quad*4+reg (HW-verified m89/m91).
    // Cout already offset to this tile's row block; local rows 0..127.
    #pragma unroll
    for (int mi = 0; mi < 4; ++mi)
        #pragma unroll
        for (int ni = 0; ni < 4; ++ni) {
            int grow = wrow0 + mi * 16 + quad * 4;
            int gcol = nt * 128 + wcol0 + ni * 16 + lm;
            #pragma unroll
            for (int rr = 0; rr < 4; ++rr)
                Cout[(size_t)(grow + rr) * TDN + gcol] = acc[mi][ni][rr];
        }
}

// ---------------------------------------------------------------------------
// Score + label-segmented reduce, fused. grid (16, 2, 8): jc (96 j), q-tile 64,
// s-tile 64. Stages hq/hs transposed (split-K partials summed, b1 folded into
// hq), 64x64 relu-dot tile (4x4 micro), spill to LDS, run-length label reduce,
// atomicAdd into aggbuf[q][c].  (unchanged — proven)
// ---------------------------------------------------------------------------
__global__ __launch_bounds__(256) void score_kernel(
    const float* __restrict__ hqp, const float* __restrict__ hsp,
    const float* __restrict__ b1, const float* __restrict__ W2,
    const int* __restrict__ labels, float* __restrict__ aggbuf)
{
    const int jc = blockIdx.x;   // 0..15
    const int qt = blockIdx.y;   // 0..1
    const int st = blockIdx.z;   // 0..7

    __shared__ float hqT[96][64];
    __shared__ float hsT[96][64];
    __shared__ float w2s[96];
    __shared__ float sc[64][68];
    __shared__ int   lab[64];

    const int tid = threadIdx.x;
    if (tid < 64) lab[tid] = labels[st * 64 + tid];

    #pragma unroll
    for (int l = 0; l < 6; ++l) {
        int idx  = tid + l * 256;         // 0..1535
        int row  = idx / 24;              // 0..63
        int quad = idx - row * 24;        // 0..23
        int j    = jc * 96 + quad * 4;
        float4 hv = *(const float4*)&b1[j];
        float4 sv = make_float4(0.f, 0.f, 0.f, 0.f);
        #pragma unroll
        for (int p = 0; p < KSPLIT; ++p) {
            float4 h = *(const float4*)&hqp[(size_t)p * QN * TDN + (size_t)(qt * 64 + row) * TDN + j];
            float4 g = *(const float4*)&hsp[(size_t)p * SN * TDN + (size_t)(st * 64 + row) * TDN + j];
            hv.x += h.x; hv.y += h.y; hv.z += h.z; hv.w += h.w;
            sv.x += g.x; sv.y += g.y; sv.z += g.z; sv.w += g.w;
        }
        hqT[quad*4+0][row] = hv.x; hqT[quad*4+1][row] = hv.y;
        hqT[quad*4+2][row] = hv.z; hqT[quad*4+3][row] = hv.w;
        hsT[quad*4+0][row] = sv.x; hsT[quad*4+1][row] = sv.y;
        hsT[quad*4+2][row] = sv.z; hsT[quad*4+3][row] = sv.w;
    }
    if (tid < 24) {
        float4 w = *(const float4*)&W2[jc * 96 + tid * 4];
        w2s[tid*4+0] = w.x; w2s[tid*4+1] = w.y;
        w2s[tid*4+2] = w.z; w2s[tid*4+3] = w.w;
    }
    __syncthreads();

    const int tx = tid & 15;
    const int ty = tid >> 4;
    float acc[4][4];
    #pragma unroll
    for (int i = 0; i < 4; ++i)
        #pragma unroll
        for (int j = 0; j < 4; ++j) acc[i][j] = 0.0f;

    #pragma unroll 4
    for (int jj = 0; jj < 96; ++jj) {
        float4 a4 = *(const float4*)&hqT[jj][ty * 4];
        float4 b4 = *(const float4*)&hsT[jj][tx * 4];
        float w = w2s[jj];
        float a[4] = {a4.x, a4.y, a4.z, a4.w};
        float b[4] = {b4.x, b4.y, b4.z, b4.w};
        #pragma unroll
        for (int i = 0; i < 4; ++i)
            #pragma unroll
            for (int j = 0; j < 4; ++j)
                acc[i][j] += w * fmaxf(a[i] + b[j], 0.0f);
    }

    #pragma unroll
    for (int i = 0; i < 4; ++i)
        *(float4*)&sc[ty * 4 + i][tx * 4] =
            make_float4(acc[i][0], acc[i][1], acc[i][2], acc[i][3]);
    __syncthreads();

    {   // run-length label reduce: thread = (q-row, 16-wide s segment)
        int row = tid >> 2;
        int seg = tid & 3;
        float* aggrow = aggbuf + (size_t)(qt * 64 + row) * CN;
        int   runc = lab[seg * 16];
        float runv = 0.0f;
        #pragma unroll
        for (int k = 0; k < 16; ++k) {
            int s = seg * 16 + k;
            int c = lab[s];
            if (c != runc) { atomicAdd(&aggrow[runc], runv); runv = 0.0f; runc = c; }
            runv += sc[row][s];
        }
        atomicAdd(&aggrow[runc], runv);
    }
}

// ---------------------------------------------------------------------------
// Finale: grid 32 x 256 — one wave per query. Histogram counts in LDS, then
// per-wave: mean, fused max+argmax, exp-sum, pred flag; lane0 atomicAdds
// -logp/QN into out[0] (zeroed by convert).  (unchanged — proven)
// ---------------------------------------------------------------------------
__global__ __launch_bounds__(256) void finale_kernel(
    const float* __restrict__ aggbuf, const int* __restrict__ labels,
    const int* __restrict__ tgt, float* __restrict__ out)
{
    __shared__ float cnt[CN];
    const int tid = threadIdx.x;
    if (tid < CN) cnt[tid] = 0.0f;
    __syncthreads();
    atomicAdd(&cnt[labels[tid]],       1.0f);
    atomicAdd(&cnt[labels[tid + 256]], 1.0f);
    __syncthreads();

    const int lane = tid & 63;
    const int q    = blockIdx.x * 4 + (tid >> 6);

    float v = aggbuf[(size_t)q * CN + lane] / fmaxf(cnt[lane], 1.0f);
    float av = v; int am = lane;
    #pragma unroll
    for (int off = 1; off < 64; off <<= 1) {
        float ov = __shfl_xor(av, off);
        int   oi = __shfl_xor(am, off);
        if (ov > av || (ov == av && oi < am)) { av = ov; am = oi; }
    }
    float m = av;
    float e = expf(v - m);
    #pragma unroll
    for (int off = 1; off < 64; off <<= 1)
        e += __shfl_xor(e, off);
    int t = tgt[q];
    float vt = __shfl(v, t, 64);
    if (lane == 0) {
        out[1 + q] = (am == t) ? 1.0f : 0.0f;
        atomicAdd(&out[0], -(vt - m - logf(e)) / (float)QN);
    }
}

extern "C" void kernel_launch(void* const* d_in, const int* in_sizes, int n_in,
                              void* d_out, int out_size, void* d_ws, size_t ws_size,
                              hipStream_t stream) {
    const float* query   = (const float*)d_in[0];
    const float* support = (const float*)d_in[1];
    const float* W1      = (const float*)d_in[2];
    const float* b1      = (const float*)d_in[3];
    const float* W2      = (const float*)d_in[4];
    // d_in[5] = b2: uniform shift, cancels under log_softmax/argmax -> unused
    const int* labels = (const int*)d_in[6];
    const int* tgt    = (const int*)d_in[7];

    float* ws     = (float*)d_ws;
    float* hqp    = ws;                    // KSPLIT*QN*TDN
    float* hsp    = hqp + HQP_ELEMS;       // KSPLIT*SN*TDN
    float* aggbuf = hsp + HSP_ELEMS;       // QN*CN  (zeroed by convert)
    short* Ah     = (short*)(aggbuf + ZERO_ELEMS);   // 16B-aligned
    short* Al     = Ah + A_FLOATS;
    short* Bh     = Al + A_FLOATS;
    short* Bl     = Bh + B_FLOATS;
    float* out    = (float*)d_out;

    hipLaunchKernelGGL(convert_kernel, dim3(1392), dim3(256), 0, stream,
                       query, support, W1, Ah, Al, Bh, Bl, aggbuf, out);
    hipLaunchKernelGGL(gemm_kernel, dim3(12, 5, 4), dim3(256), 0, stream,
                       Ah, Al, Bh, Bl, hqp, hsp);
    hipLaunchKernelGGL(score_kernel, dim3(16, 2, 8), dim3(256), 0, stream,
                       hqp, hsp, b1, W2, labels, aggbuf);
    hipLaunchKernelGGL(finale_kernel, dim3(32), dim3(256), 0, stream,
                       aggbuf, labels, tgt, out);
}